// Round 1
// baseline (1181.383 us; speedup 1.0000x reference)
//
#include <hip/hip_runtime.h>
#include <math.h>

#define HD 256
#define NEG 0.2f
#define BN_EPS 1e-5f

// ---------------- CSR build (by dst) ----------------
__global__ void hist_kernel(const int* __restrict__ dst, int* __restrict__ cnt, int E) {
  int i = blockIdx.x * blockDim.x + threadIdx.x;
  if (i < E) atomicAdd(&cnt[dst[i]], 1);
}

__global__ __launch_bounds__(1024) void scan_kernel(const int* __restrict__ cnt,
                                                    int* __restrict__ rowptr, int n) {
  __shared__ int sdata[1024];
  int t = threadIdx.x;
  int ipt = (n + 1023) >> 10;
  int base = t * ipt;
  int s = 0;
  for (int i = 0; i < ipt; ++i) { int idx = base + i; if (idx < n) s += cnt[idx]; }
  sdata[t] = s;
  __syncthreads();
  for (int off = 1; off < 1024; off <<= 1) {
    int v = (t >= off) ? sdata[t - off] : 0;
    __syncthreads();
    sdata[t] += v;
    __syncthreads();
  }
  int run = (t == 0) ? 0 : sdata[t - 1];
  for (int i = 0; i < ipt; ++i) {
    int idx = base + i;
    if (idx < n) { run += cnt[idx]; rowptr[idx + 1] = run; }
  }
  if (t == 0) rowptr[0] = 0;
}

__global__ void scatter_kernel(const int* __restrict__ dst, const int* __restrict__ rowptr,
                               int* __restrict__ fill, int* __restrict__ esort, int E) {
  int i = blockIdx.x * blockDim.x + threadIdx.x;
  if (i < E) {
    int d = dst[i];
    int pos = atomicAdd(&fill[d], 1);
    esort[rowptr[d] + pos] = i;
  }
}

// ---------------- dual GEMM: xl = h@Wl, xr = h@Wr ----------------
// block: 256 threads (one per output column), 16 rows per block, LDS-staged h tile.
__global__ __launch_bounds__(256) void gemm_dual(const float* __restrict__ h, int K,
                                                 const float* __restrict__ Wl,
                                                 const float* __restrict__ Wr,
                                                 float* __restrict__ xl, float* __restrict__ xr,
                                                 int n) {
  __shared__ float hs[16 * 256];
  int r0 = blockIdx.x * 16;
  int t = threadIdx.x;
  int nr = min(16, n - r0);
  int tot = nr * K;
  for (int i = t; i < tot; i += 256) {
    int r = i / K;
    int k = i - r * K;
    hs[r * K + k] = h[(size_t)(r0 + r) * K + k];
  }
  __syncthreads();
  float accl[16], accr[16];
#pragma unroll
  for (int r = 0; r < 16; ++r) { accl[r] = 0.f; accr[r] = 0.f; }
  int j = t;
  for (int k = 0; k < K; ++k) {
    float wl = Wl[(size_t)k * HD + j];
    float wr = Wr[(size_t)k * HD + j];
#pragma unroll
    for (int r = 0; r < 16; ++r) {
      float hv = hs[r * K + k];
      accl[r] += hv * wl;
      accr[r] += hv * wr;
    }
  }
  for (int r = 0; r < nr; ++r) {
    xl[(size_t)(r0 + r) * HD + j] = accl[r];
    xr[(size_t)(r0 + r) * HD + j] = accr[r];
  }
}

// ---------------- fused GATv2 layer: edge scores + online softmax + aggregate ----------------
// One wave (64 lanes) per node; lane covers columns {l, l+64, l+128, l+192}.
// q=0,1 -> head 0; q=2,3 -> head 1 (column = head*128 + o).
__global__ __launch_bounds__(256) void gat_kernel(const float* __restrict__ xl,
                                                  const float* __restrict__ xr,
                                                  const int* __restrict__ src,
                                                  const int* __restrict__ rowptr,
                                                  const int* __restrict__ esort,
                                                  const float* __restrict__ ea,
                                                  const float* __restrict__ We,
                                                  const float* __restrict__ att,
                                                  const float* __restrict__ bc,
                                                  float* __restrict__ hout, int n) {
  __shared__ float WeS[16 * 256];
  int t = threadIdx.x;
  for (int i = t; i < 16 * 256; i += 256) WeS[i] = We[i];
  __syncthreads();
  int lane = t & 63;
  int wid = t >> 6;
  int node = blockIdx.x * 4 + wid;
  if (node >= n) return;

  int c0 = lane, c1 = lane + 64, c2 = lane + 128, c3 = lane + 192;
  float a0 = att[c0], a1 = att[c1], a2 = att[c2], a3 = att[c3];
  size_t nb = (size_t)node * HD;
  float xr0 = xr[nb + c0], xr1 = xr[nb + c1], xr2 = xr[nb + c2], xr3 = xr[nb + c3];

  float acc0 = 0.f, acc1 = 0.f, acc2 = 0.f, acc3 = 0.f;
  float m0 = -3.0e38f, m1 = -3.0e38f, d0 = 0.f, d1 = 0.f;

  int pbeg = rowptr[node], pend = rowptr[node + 1];
  for (int p = pbeg; p < pend; ++p) {
    int e = esort[p];          // wave-uniform
    int s = src[e];            // wave-uniform
    const float* xls = xl + (size_t)s * HD;
    float x0 = xls[c0], x1 = xls[c1], x2 = xls[c2], x3 = xls[c3];
    const float* ear = ea + (size_t)e * 16;
    float e0 = 0.f, e1 = 0.f, e2 = 0.f, e3 = 0.f;
#pragma unroll
    for (int k = 0; k < 16; ++k) {
      float av = ear[k];
      e0 += av * WeS[k * 256 + c0];
      e1 += av * WeS[k * 256 + c1];
      e2 += av * WeS[k * 256 + c2];
      e3 += av * WeS[k * 256 + c3];
    }
    float v0 = x0 + xr0 + e0, v1 = x1 + xr1 + e1, v2 = x2 + xr2 + e2, v3 = x3 + xr3 + e3;
    float l0 = v0 > 0.f ? v0 : NEG * v0;
    float l1 = v1 > 0.f ? v1 : NEG * v1;
    float l2 = v2 > 0.f ? v2 : NEG * v2;
    float l3 = v3 > 0.f ? v3 : NEG * v3;
    float p0 = l0 * a0 + l1 * a1;  // head 0 partial
    float p1 = l2 * a2 + l3 * a3;  // head 1 partial
#pragma unroll
    for (int off = 32; off >= 1; off >>= 1) {
      p0 += __shfl_xor(p0, off);
      p1 += __shfl_xor(p1, off);
    }
    // online softmax, head 0
    float r0s, pe0;
    if (p0 > m0) { r0s = __expf(m0 - p0); m0 = p0; pe0 = 1.f; }
    else         { r0s = 1.f; pe0 = __expf(p0 - m0); }
    d0 = d0 * r0s + pe0;
    acc0 = acc0 * r0s + pe0 * x0;
    acc1 = acc1 * r0s + pe0 * x1;
    // head 1
    float r1s, pe1;
    if (p1 > m1) { r1s = __expf(m1 - p1); m1 = p1; pe1 = 1.f; }
    else         { r1s = 1.f; pe1 = __expf(p1 - m1); }
    d1 = d1 * r1s + pe1;
    acc2 = acc2 * r1s + pe1 * x2;
    acc3 = acc3 * r1s + pe1 * x3;
  }
  float i0 = d0 > 0.f ? 1.f / d0 : 0.f;
  float i1 = d1 > 0.f ? 1.f / d1 : 0.f;
  hout[nb + c0] = acc0 * i0 + bc[c0];
  hout[nb + c1] = acc1 * i0 + bc[c1];
  hout[nb + c2] = acc2 * i1 + bc[c2];
  hout[nb + c3] = acc3 * i1 + bc[c3];
}

// ---------------- BatchNorm (training-mode batch stats) + ReLU ----------------
__global__ __launch_bounds__(256) void bn_stats(const float* __restrict__ h,
                                                float* __restrict__ sums, int n) {
  int c = threadIdx.x;
  int rows_per = (n + gridDim.x - 1) / gridDim.x;
  int r0 = blockIdx.x * rows_per;
  int r1 = min(n, r0 + rows_per);
  float s = 0.f, s2 = 0.f;
  for (int r = r0; r < r1; ++r) {
    float v = h[(size_t)r * HD + c];
    s += v;
    s2 += v * v;
  }
  atomicAdd(&sums[c], s);
  atomicAdd(&sums[HD + c], s2);
}

__global__ void bn_finalize(const float* __restrict__ sums, const float* __restrict__ gamma,
                            const float* __restrict__ beta, float* __restrict__ ss, float n) {
  int c = threadIdx.x;
  float mean = sums[c] / n;
  float var = sums[HD + c] / n - mean * mean;
  float sc = gamma[c] * rsqrtf(var + BN_EPS);
  ss[c] = sc;
  ss[HD + c] = beta[c] - mean * sc;
}

__global__ void bn_apply(float* __restrict__ h, const float* __restrict__ ss, int total) {
  int i = blockIdx.x * blockDim.x + threadIdx.x;
  if (i < total) {
    int c = i & (HD - 1);
    float v = h[i] * ss[c] + ss[HD + c];
    h[i] = fmaxf(v, 0.f);
  }
}

// ---------------- pooling ----------------
__global__ void count_kernel(const int* __restrict__ batch, float* __restrict__ cnt, int n) {
  int i = blockIdx.x * blockDim.x + threadIdx.x;
  if (i < n) atomicAdd(&cnt[batch[i]], 1.0f);
}

__global__ __launch_bounds__(256) void pool_kernel(const float* __restrict__ h,
                                                   const int* __restrict__ batch,
                                                   float* __restrict__ pooled, int n) {
  int c = threadIdx.x;
  int rows_per = (n + gridDim.x - 1) / gridDim.x;
  int r0 = blockIdx.x * rows_per;
  int r1 = min(n, r0 + rows_per);
  if (r0 >= r1) return;
  int cur = batch[r0];
  float acc = 0.f;
  for (int r = r0; r < r1; ++r) {
    int b = batch[r];
    if (b != cur) {
      atomicAdd(&pooled[(size_t)cur * HD + c], acc);
      acc = 0.f;
      cur = b;
    }
    acc += h[(size_t)r * HD + c];
  }
  atomicAdd(&pooled[(size_t)cur * HD + c], acc);
}

// ---------------- MLP head ----------------
__global__ __launch_bounds__(256) void mlp1_kernel(const float* __restrict__ pooled,
                                                   const float* __restrict__ cnt,
                                                   const float* __restrict__ gf,
                                                   const float* __restrict__ W1,
                                                   const float* __restrict__ b1,
                                                   float* __restrict__ z1, int GD) {
  __shared__ float in_s[264];
  int b = blockIdx.x, t = threadIdx.x;
  float cv = cnt[b];
  float inv = cv > 0.f ? 1.f / cv : 0.f;
  in_s[t] = pooled[(size_t)b * HD + t] * inv;
  if (t < GD) in_s[HD + t] = gf[b * GD + t];
  __syncthreads();
  float acc = b1[t];
  for (int k = 0; k < HD + 8; ++k) acc += in_s[k] * W1[(size_t)k * 256 + t];
  z1[b * 256 + t] = fmaxf(acc, 0.f);
}

__global__ __launch_bounds__(128) void mlp2_kernel(const float* __restrict__ z1,
                                                   const float* __restrict__ W2,
                                                   const float* __restrict__ b2,
                                                   float* __restrict__ z2) {
  __shared__ float zs[256];
  int b = blockIdx.x, t = threadIdx.x;
  zs[t] = z1[b * 256 + t];
  zs[t + 128] = z1[b * 256 + t + 128];
  __syncthreads();
  float acc = b2[t];
  for (int k = 0; k < 256; ++k) acc += zs[k] * W2[k * 128 + t];
  z2[b * 128 + t] = fmaxf(acc, 0.f);
}

__global__ __launch_bounds__(128) void mlp3_kernel(const float* __restrict__ z2,
                                                   const float* __restrict__ W3,
                                                   const float* __restrict__ b3,
                                                   float* __restrict__ out) {
  __shared__ float zs[128];
  int b = blockIdx.x, t = threadIdx.x;
  zs[t] = z2[b * 128 + t];
  __syncthreads();
  if (t < 100) {
    float acc = b3[t];
    for (int k = 0; k < 128; ++k) acc += zs[k] * W3[k * 100 + t];
    out[b * 100 + t] = acc;
  }
}

extern "C" void kernel_launch(void* const* d_in, const int* in_sizes, int n_in,
                              void* d_out, int out_size, void* d_ws, size_t ws_size,
                              hipStream_t stream) {
  (void)n_in; (void)out_size; (void)ws_size;
  const float* x      = (const float*)d_in[0];
  const int*   ei     = (const int*)d_in[1];
  const float* ea     = (const float*)d_in[2];
  const int*   batch  = (const int*)d_in[3];
  const float* gf     = (const float*)d_in[4];
  const int E = in_sizes[1] / 2;
  const int N = in_sizes[3];
  const int B = in_sizes[4] / 8;
  const int GD = 8;
  const int* srcA = ei;
  const int* dstA = ei + E;

  const float *Wl[3], *Wr[3], *We[3], *att[3], *bc[3], *gamma[3], *beta[3];
  for (int l = 0; l < 3; ++l) {
    int base = 5 + 7 * l;
    Wl[l]    = (const float*)d_in[base + 0];
    Wr[l]    = (const float*)d_in[base + 1];
    We[l]    = (const float*)d_in[base + 2];
    att[l]   = (const float*)d_in[base + 3];
    bc[l]    = (const float*)d_in[base + 4];
    gamma[l] = (const float*)d_in[base + 5];
    beta[l]  = (const float*)d_in[base + 6];
  }
  const float* W1 = (const float*)d_in[26];
  const float* b1 = (const float*)d_in[27];
  const float* W2 = (const float*)d_in[28];
  const float* b2 = (const float*)d_in[29];
  const float* W3 = (const float*)d_in[30];
  const float* b3 = (const float*)d_in[31];

  char* w = (char*)d_ws;
  size_t off = 0;
  auto A = [&](size_t bytes) { size_t o = off; off = (off + bytes + 255) & ~(size_t)255; return o; };
  int*   rowptr = (int*)(w + A((size_t)(N + 1) * 4));
  int*   fill   = (int*)(w + A((size_t)N * 4));
  int*   esort  = (int*)(w + A((size_t)E * 4));
  float* hbuf   = (float*)(w + A((size_t)N * HD * 4));
  float* xlb    = (float*)(w + A((size_t)N * HD * 4));
  float* xrb    = (float*)(w + A((size_t)N * HD * 4));
  float* bnsums = (float*)(w + A(2 * HD * 4));
  float* bnss   = (float*)(w + A(2 * HD * 4));
  float* pooled = (float*)(w + A((size_t)B * HD * 4 + B * 4));
  float* cntb   = pooled + (size_t)B * HD;
  float* z1     = (float*)(w + A((size_t)B * 256 * 4));
  float* z2     = (float*)(w + A((size_t)B * 128 * 4));

  // CSR by dst
  hipMemsetAsync(fill, 0, (size_t)N * 4, stream);
  hist_kernel<<<(E + 255) / 256, 256, 0, stream>>>(dstA, fill, E);
  scan_kernel<<<1, 1024, 0, stream>>>(fill, rowptr, N);
  hipMemsetAsync(fill, 0, (size_t)N * 4, stream);
  scatter_kernel<<<(E + 255) / 256, 256, 0, stream>>>(dstA, rowptr, fill, esort, E);

  const float* hin = x;
  for (int l = 0; l < 3; ++l) {
    int K = (l == 0) ? 6 : HD;
    gemm_dual<<<(N + 15) / 16, 256, 0, stream>>>(hin, K, Wl[l], Wr[l], xlb, xrb, N);
    gat_kernel<<<(N + 3) / 4, 256, 0, stream>>>(xlb, xrb, srcA, rowptr, esort, ea,
                                                We[l], att[l], bc[l], hbuf, N);
    hipMemsetAsync(bnsums, 0, 2 * HD * 4, stream);
    bn_stats<<<256, 256, 0, stream>>>(hbuf, bnsums, N);
    bn_finalize<<<1, HD, 0, stream>>>(bnsums, gamma[l], beta[l], bnss, (float)N);
    bn_apply<<<((size_t)N * HD + 255) / 256, 256, 0, stream>>>(hbuf, bnss, N * HD);
    hin = hbuf;
  }

  hipMemsetAsync(pooled, 0, (size_t)B * HD * 4 + B * 4, stream);
  count_kernel<<<(N + 255) / 256, 256, 0, stream>>>(batch, cntb, N);
  pool_kernel<<<256, 256, 0, stream>>>(hbuf, batch, pooled, N);
  mlp1_kernel<<<B, 256, 0, stream>>>(pooled, cntb, gf, W1, b1, z1, GD);
  mlp2_kernel<<<B, 128, 0, stream>>>(z1, W2, b2, z2);
  mlp3_kernel<<<B, 128, 0, stream>>>(z2, W3, b3, (float*)d_out);
}

// Round 4
// 1038.870 us; speedup vs baseline: 1.1372x; 1.1372x over previous
//
#include <hip/hip_runtime.h>
#include <math.h>

#define HD 256
#define NEG 0.2f
#define BN_EPS 1e-5f
#define GSTAT 64  // deterministic BN partial blocks

// ---------------- CSR build (by dst) ----------------
__global__ void hist_kernel(const int* __restrict__ dst, int* __restrict__ cnt, int E) {
  int i = blockIdx.x * blockDim.x + threadIdx.x;
  if (i < E) atomicAdd(&cnt[dst[i]], 1);
}

__global__ __launch_bounds__(1024) void scan_kernel(const int* __restrict__ cnt,
                                                    int* __restrict__ rowptr, int n) {
  __shared__ int sdata[1024];
  int t = threadIdx.x;
  int ipt = (n + 1023) >> 10;
  int base = t * ipt;
  int s = 0;
  for (int i = 0; i < ipt; ++i) { int idx = base + i; if (idx < n) s += cnt[idx]; }
  sdata[t] = s;
  __syncthreads();
  for (int off = 1; off < 1024; off <<= 1) {
    int v = (t >= off) ? sdata[t - off] : 0;
    __syncthreads();
    sdata[t] += v;
    __syncthreads();
  }
  int run = (t == 0) ? 0 : sdata[t - 1];
  for (int i = 0; i < ipt; ++i) {
    int idx = base + i;
    if (idx < n) { run += cnt[idx]; rowptr[idx + 1] = run; }
  }
  if (t == 0) rowptr[0] = 0;
}

// arrival order nondeterministic -> list ORDER varies; sorted later in gat layer 0
__global__ void scatter_kernel(const int* __restrict__ dst, const int* __restrict__ rowptr,
                               int* __restrict__ fill, int* __restrict__ esort, int E) {
  int i = blockIdx.x * blockDim.x + threadIdx.x;
  if (i < E) {
    int d = dst[i];
    int pos = atomicAdd(&fill[d], 1);
    esort[rowptr[d] + pos] = i;
  }
}

// ---------------- dual GEMM K=6 (layer 0) ----------------
__global__ __launch_bounds__(256) void gemm_dual6(const float* __restrict__ h,
                                                  const float* __restrict__ Wl,
                                                  const float* __restrict__ Wr,
                                                  float* __restrict__ xlo, float* __restrict__ xro,
                                                  int n) {
  __shared__ float hs[32 * 6];
  int r0 = blockIdx.x * 32;
  int t = threadIdx.x;
  int nr = min(32, n - r0);
  int tot = nr * 6;
  for (int i = t; i < tot; i += 256) hs[i] = h[(size_t)r0 * 6 + i];
  __syncthreads();
  float accl[32], accr[32];
#pragma unroll
  for (int r = 0; r < 32; ++r) { accl[r] = 0.f; accr[r] = 0.f; }
  int j = t;
  for (int k = 0; k < 6; ++k) {
    float wl = Wl[k * HD + j];
    float wr = Wr[k * HD + j];
#pragma unroll
    for (int r = 0; r < 32; ++r) {
      float hv = hs[r * 6 + k];
      accl[r] += hv * wl;
      accr[r] += hv * wr;
    }
  }
  for (int r = 0; r < nr; ++r) {
    xlo[(size_t)(r0 + r) * HD + j] = accl[r];
    xro[(size_t)(r0 + r) * HD + j] = accr[r];
  }
}

// ---------------- dual GEMM K=256, BN(from partials)+ReLU fused on input ----------------
__global__ __launch_bounds__(256) void gemm_dual256(const float* __restrict__ h,
                                                    const float* __restrict__ partials,
                                                    const float* __restrict__ gamma,
                                                    const float* __restrict__ beta,
                                                    const float* __restrict__ Wl,
                                                    const float* __restrict__ Wr,
                                                    float* __restrict__ xlo, float* __restrict__ xro,
                                                    int n, float nf) {
  __shared__ float hs[32 * 256];
  __shared__ float ssc[256], ssh[256];
  int t = threadIdx.x;
  // deterministic BN finalize (fixed-order reduction over GSTAT partials)
  {
    float s = 0.f, s2 = 0.f;
    for (int g = 0; g < GSTAT; ++g) {
      s += partials[g * 512 + t];
      s2 += partials[g * 512 + 256 + t];
    }
    float mean = s / nf;
    float var = s2 / nf - mean * mean;
    float sc = gamma[t] * rsqrtf(var + BN_EPS);
    ssc[t] = sc;
    ssh[t] = beta[t] - mean * sc;
  }
  int r0 = blockIdx.x * 32;
  int nr = min(32, n - r0);
  __syncthreads();
  const float4* hsrc = (const float4*)(h + (size_t)r0 * HD);
  float4* hdst = (float4*)hs;
  int totv = nr * 64;
  for (int i = t; i < totv; i += 256) {
    int cv = (i & 63) * 4;
    float4 v = hsrc[i];
    v.x = fmaxf(v.x * ssc[cv + 0] + ssh[cv + 0], 0.f);
    v.y = fmaxf(v.y * ssc[cv + 1] + ssh[cv + 1], 0.f);
    v.z = fmaxf(v.z * ssc[cv + 2] + ssh[cv + 2], 0.f);
    v.w = fmaxf(v.w * ssc[cv + 3] + ssh[cv + 3], 0.f);
    hdst[i] = v;
  }
  __syncthreads();
  float accl[32], accr[32];
#pragma unroll
  for (int r = 0; r < 32; ++r) { accl[r] = 0.f; accr[r] = 0.f; }
  int j = t;
  for (int k = 0; k < 256; k += 4) {
    float wl0 = Wl[(size_t)(k + 0) * HD + j];
    float wl1 = Wl[(size_t)(k + 1) * HD + j];
    float wl2 = Wl[(size_t)(k + 2) * HD + j];
    float wl3 = Wl[(size_t)(k + 3) * HD + j];
    float wr0 = Wr[(size_t)(k + 0) * HD + j];
    float wr1 = Wr[(size_t)(k + 1) * HD + j];
    float wr2 = Wr[(size_t)(k + 2) * HD + j];
    float wr3 = Wr[(size_t)(k + 3) * HD + j];
#pragma unroll
    for (int r = 0; r < 32; ++r) {
      float4 hv = *(const float4*)&hs[r * 256 + k];
      accl[r] += hv.x * wl0;
      accl[r] += hv.y * wl1;
      accl[r] += hv.z * wl2;
      accl[r] += hv.w * wl3;
      accr[r] += hv.x * wr0;
      accr[r] += hv.y * wr1;
      accr[r] += hv.z * wr2;
      accr[r] += hv.w * wr3;
    }
  }
  for (int r = 0; r < nr; ++r) {
    xlo[(size_t)(r0 + r) * HD + j] = accl[r];
    xro[(size_t)(r0 + r) * HD + j] = accr[r];
  }
}

// ---------------- fused GATv2 layer ----------------
// One wave per node; lane l -> 4 contiguous cols c=4l; lanes 0-31 head 0, 32-63 head 1.
// dosort=1 (layer 0): bitonic-sort this node's edge list by edge id (deterministic order),
// write back for layers 1-2. Everything downstream is then bitwise-reproducible.
__global__ __launch_bounds__(256) void gat_kernel(const float* __restrict__ xl,
                                                  const float* __restrict__ xr,
                                                  const int* __restrict__ src,
                                                  const int* __restrict__ rowptr,
                                                  int* __restrict__ esort,
                                                  const float* __restrict__ ea,
                                                  const float* __restrict__ We,
                                                  const float* __restrict__ att,
                                                  const float* __restrict__ bc,
                                                  float* __restrict__ hout, int n, int dosort) {
  int t = threadIdx.x;
  int lane = t & 63;
  int node = __builtin_amdgcn_readfirstlane(blockIdx.x * 4 + (t >> 6));
  if (node >= n) return;
  int c = lane * 4;

  int pbeg = rowptr[node], pend = rowptr[node + 1];
  int deg = pend - pbeg;

  if (dosort && deg > 1) {
    if (deg <= 64) {
      int v = (lane < deg) ? esort[pbeg + lane] : 0x7fffffff;
#pragma unroll
      for (int k = 2; k <= 64; k <<= 1) {
#pragma unroll
        for (int j = k >> 1; j >= 1; j >>= 1) {
          int u = __shfl_xor(v, j);
          bool keepmin = (((lane & k) == 0) == ((lane & j) == 0));
          v = keepmin ? (v < u ? v : u) : (v > u ? v : u);
        }
      }
      if (lane < deg) esort[pbeg + lane] = v;
    } else if (lane == 0) {
      // selection sort fallback (deg>64 ~ unreachable for Poisson(16))
      for (int a = pbeg; a < pend - 1; ++a) {
        int mi = a;
        for (int b2 = a + 1; b2 < pend; ++b2)
          if (esort[b2] < esort[mi]) mi = b2;
        int tmp = esort[a]; esort[a] = esort[mi]; esort[mi] = tmp;
      }
    }
    __builtin_amdgcn_s_waitcnt(0);  // own stores visible before re-read
  }

  float4 w4[16];
#pragma unroll
  for (int k = 0; k < 16; ++k) w4[k] = *(const float4*)(We + k * HD + c);
  float4 att4 = *(const float4*)(att + c);
  size_t nb = (size_t)node * HD;
  float4 xr4 = *(const float4*)(xr + nb + c);

  float4 acc = make_float4(0.f, 0.f, 0.f, 0.f);
  float m = -3.0e38f, d = 0.f;

  for (int p = pbeg; p < pend; p += 4) {
    int nbt = pend - p;
    if (nbt > 4) nbt = 4;
    int ei[4], si[4];
    float4 xv[4];
#pragma unroll
    for (int i = 0; i < 4; ++i) {
      if (i < nbt) {
        ei[i] = __builtin_amdgcn_readfirstlane(esort[p + i]);
        si[i] = __builtin_amdgcn_readfirstlane(src[ei[i]]);
      }
    }
#pragma unroll
    for (int i = 0; i < 4; ++i) {
      if (i < nbt) xv[i] = *(const float4*)(xl + (size_t)si[i] * HD + c);
    }
#pragma unroll
    for (int i = 0; i < 4; ++i) {
      if (i < nbt) {
        const float* ear = ea + (size_t)ei[i] * 16;
        float4 v;
        v.x = xv[i].x + xr4.x;
        v.y = xv[i].y + xr4.y;
        v.z = xv[i].z + xr4.z;
        v.w = xv[i].w + xr4.w;
#pragma unroll
        for (int k = 0; k < 16; ++k) {
          float av = ear[k];
          v.x += av * w4[k].x;
          v.y += av * w4[k].y;
          v.z += av * w4[k].z;
          v.w += av * w4[k].w;
        }
        float l0 = v.x > 0.f ? v.x : NEG * v.x;
        float l1 = v.y > 0.f ? v.y : NEG * v.y;
        float l2 = v.z > 0.f ? v.z : NEG * v.z;
        float l3 = v.w > 0.f ? v.w : NEG * v.w;
        float pv = l0 * att4.x + l1 * att4.y + l2 * att4.z + l3 * att4.w;
        pv += __shfl_xor(pv, 16);
        pv += __shfl_xor(pv, 8);
        pv += __shfl_xor(pv, 4);
        pv += __shfl_xor(pv, 2);
        pv += __shfl_xor(pv, 1);
        float rs, pe;
        if (pv > m) { rs = __expf(m - pv); m = pv; pe = 1.f; }
        else        { rs = 1.f; pe = __expf(pv - m); }
        d = d * rs + pe;
        acc.x = acc.x * rs + pe * xv[i].x;
        acc.y = acc.y * rs + pe * xv[i].y;
        acc.z = acc.z * rs + pe * xv[i].z;
        acc.w = acc.w * rs + pe * xv[i].w;
      }
    }
  }
  float inv = d > 0.f ? 1.f / d : 0.f;
  float4 bc4 = *(const float4*)(bc + c);
  float4 o;
  o.x = acc.x * inv + bc4.x;
  o.y = acc.y * inv + bc4.y;
  o.z = acc.z * inv + bc4.z;
  o.w = acc.w * inv + bc4.w;
  *(float4*)(hout + nb + c) = o;
}

// ---------------- deterministic BN partials ----------------
__global__ __launch_bounds__(256) void bn_stats(const float* __restrict__ h,
                                                float* __restrict__ partials, int n) {
  int c = threadIdx.x;
  int g = blockIdx.x;
  int rows = (n + GSTAT - 1) / GSTAT;
  int r0 = g * rows;
  int r1 = min(n, r0 + rows);
  float s = 0.f, s2 = 0.f;
  for (int r = r0; r < r1; ++r) {
    float v = h[(size_t)r * HD + c];
    s += v;
    s2 += v * v;
  }
  partials[g * 512 + c] = s;
  partials[g * 512 + 256 + c] = s2;
}

// ---------------- fused head: BN+ReLU + mean-pool + 3-layer MLP ----------------
// one block per graph; deterministic (binary search on sorted batch, no atomics)
__global__ __launch_bounds__(256) void head_kernel(const float* __restrict__ h,
                                                   const float* __restrict__ partials,
                                                   const float* __restrict__ gamma,
                                                   const float* __restrict__ beta,
                                                   const int* __restrict__ batch,
                                                   const float* __restrict__ gf,
                                                   const float* __restrict__ W1,
                                                   const float* __restrict__ b1,
                                                   const float* __restrict__ W2,
                                                   const float* __restrict__ b2,
                                                   const float* __restrict__ W3,
                                                   const float* __restrict__ b3,
                                                   float* __restrict__ out, int n, float nf) {
  int b = blockIdx.x, t = threadIdx.x;
  float s = 0.f, s2 = 0.f;
  for (int g = 0; g < GSTAT; ++g) {
    s += partials[g * 512 + t];
    s2 += partials[g * 512 + 256 + t];
  }
  float mean = s / nf;
  float var = s2 / nf - mean * mean;
  float sc = gamma[t] * rsqrtf(var + BN_EPS);
  float sh = beta[t] - mean * sc;

  int lo = 0, hi = n;
  while (lo < hi) { int mid = (lo + hi) >> 1; if (batch[mid] < b) lo = mid + 1; else hi = mid; }
  int s0 = lo;
  lo = 0; hi = n;
  while (lo < hi) { int mid = (lo + hi) >> 1; if (batch[mid] < b + 1) lo = mid + 1; else hi = mid; }
  int s1 = lo;

  float acc = 0.f;
  for (int r = s0; r < s1; ++r) acc += fmaxf(h[(size_t)r * HD + t] * sc + sh, 0.f);

  __shared__ float in_s[264];
  __shared__ float z1s[256];
  __shared__ float z2s[128];
  float cnt = (float)(s1 - s0);
  in_s[t] = (s1 > s0) ? acc / cnt : 0.f;
  if (t < 8) in_s[HD + t] = gf[b * 8 + t];
  __syncthreads();
  float z = b1[t];
  for (int k = 0; k < 264; ++k) z += in_s[k] * W1[(size_t)k * 256 + t];
  z1s[t] = fmaxf(z, 0.f);
  __syncthreads();
  if (t < 128) {
    float a2 = b2[t];
    for (int k = 0; k < 256; ++k) a2 += z1s[k] * W2[k * 128 + t];
    z2s[t] = fmaxf(a2, 0.f);
  }
  __syncthreads();
  if (t < 100) {
    float o = b3[t];
    for (int k = 0; k < 128; ++k) o += z2s[k] * W3[k * 100 + t];
    out[b * 100 + t] = o;
  }
}

extern "C" void kernel_launch(void* const* d_in, const int* in_sizes, int n_in,
                              void* d_out, int out_size, void* d_ws, size_t ws_size,
                              hipStream_t stream) {
  (void)n_in; (void)out_size; (void)ws_size;
  const float* x      = (const float*)d_in[0];
  const int*   ei     = (const int*)d_in[1];
  const float* ea     = (const float*)d_in[2];
  const int*   batch  = (const int*)d_in[3];
  const float* gf     = (const float*)d_in[4];
  const int E = in_sizes[1] / 2;
  const int N = in_sizes[3];
  const int B = in_sizes[4] / 8;
  const int* srcA = ei;
  const int* dstA = ei + E;

  const float *Wl[3], *Wr[3], *We[3], *att[3], *bc[3], *gamma[3], *beta[3];
  for (int l = 0; l < 3; ++l) {
    int base = 5 + 7 * l;
    Wl[l]    = (const float*)d_in[base + 0];
    Wr[l]    = (const float*)d_in[base + 1];
    We[l]    = (const float*)d_in[base + 2];
    att[l]   = (const float*)d_in[base + 3];
    bc[l]    = (const float*)d_in[base + 4];
    gamma[l] = (const float*)d_in[base + 5];
    beta[l]  = (const float*)d_in[base + 6];
  }
  const float* W1 = (const float*)d_in[26];
  const float* b1 = (const float*)d_in[27];
  const float* W2 = (const float*)d_in[28];
  const float* b2 = (const float*)d_in[29];
  const float* W3 = (const float*)d_in[30];
  const float* b3 = (const float*)d_in[31];

  char* w = (char*)d_ws;
  size_t off = 0;
  auto A = [&](size_t bytes) { size_t o = off; off = (off + bytes + 255) & ~(size_t)255; return o; };
  int*   rowptr   = (int*)(w + A((size_t)(N + 1) * 4));
  int*   fill     = (int*)(w + A((size_t)2 * N * 4));   // [0,N): hist, [N,2N): scatter
  int*   esort    = (int*)(w + A((size_t)E * 4));
  float* hbuf     = (float*)(w + A((size_t)N * HD * 4));
  float* xlb      = (float*)(w + A((size_t)N * HD * 4));
  float* xrb      = (float*)(w + A((size_t)N * HD * 4));
  float* partials = (float*)(w + A((size_t)GSTAT * 512 * 4));

  // CSR by dst (content deterministic; order fixed by gat layer-0 sort)
  hipMemsetAsync(fill, 0, (size_t)2 * N * 4, stream);
  hist_kernel<<<(E + 255) / 256, 256, 0, stream>>>(dstA, fill, E);
  scan_kernel<<<1, 1024, 0, stream>>>(fill, rowptr, N);
  scatter_kernel<<<(E + 255) / 256, 256, 0, stream>>>(dstA, rowptr, fill + N, esort, E);

  for (int l = 0; l < 3; ++l) {
    if (l == 0) {
      gemm_dual6<<<(N + 31) / 32, 256, 0, stream>>>(x, Wl[0], Wr[0], xlb, xrb, N);
    } else {
      gemm_dual256<<<(N + 31) / 32, 256, 0, stream>>>(hbuf, partials, gamma[l - 1], beta[l - 1],
                                                      Wl[l], Wr[l], xlb, xrb, N, (float)N);
    }
    gat_kernel<<<(N + 3) / 4, 256, 0, stream>>>(xlb, xrb, srcA, rowptr, esort, ea,
                                                We[l], att[l], bc[l], hbuf, N, l == 0 ? 1 : 0);
    bn_stats<<<GSTAT, 256, 0, stream>>>(hbuf, partials, N);
  }

  head_kernel<<<B, 256, 0, stream>>>(hbuf, partials, gamma[2], beta[2], batch, gf,
                                     W1, b1, W2, b2, W3, b3, (float*)d_out, N, (float)N);
}